// Round 15
// baseline (150.811 us; speedup 1.0000x reference)
//
#include <hip/hip_runtime.h>
#include <cstdint>
#include <cstddef>

// ---------------------------------------------------------------------------
// Flow_24429773980225 — round 14: r10 tail VERBATIM; gemm_main single-buffer
// 128² (32 KiB LDS -> ~4 blocks/CU cross-block overlap, m97 discipline).
//   s[r]  = <node_t[r], t[r]> + <x_n[r], uK> + c1,  t = x_n@M1^T + uQ
//   M1    = WQ^T WK,  uQ = WQ^T bK,  uK = WK^T bQ,  c1 = <bQ,bK>
//   dg    = softmax_b(s/128)
//   vw    = x_n@M2^T + bvw,  M2 = WO·WV,  bvw = WO·bV
//   out[r]= xe[r] + c0 + sum_c gelu(dg[r]*vw[r,c] + bO[c])·vN[c]
// ---------------------------------------------------------------------------

typedef __attribute__((ext_vector_type(8))) short bfx8;   // 8 bf16
typedef __attribute__((ext_vector_type(4))) short s16x4;  // 4 bf16
typedef __attribute__((ext_vector_type(4))) float f32x4;  // MFMA acc

#define N_SEQ 2048
#define M_TOT 16384   // B*N
#define NT 16         // K / 64

__device__ __forceinline__ unsigned short f2bf(float f) {
  unsigned int u = __float_as_uint(f);
  return (unsigned short)((u + 0x7fffu + ((u >> 16) & 1u)) >> 16);  // RNE
}
__device__ __forceinline__ float bf2f(short s) {
  return __uint_as_float(((unsigned int)(unsigned short)s) << 16);
}
__device__ __forceinline__ float gelu_exact(float g) {
  return 0.5f * g * (1.0f + erff(g * 0.70710678118654752f));
}
__device__ __forceinline__ void gload16(const void* g, void* l) {
  __builtin_amdgcn_global_load_lds(
      (const __attribute__((address_space(1))) unsigned int*)g,
      (__attribute__((address_space(3))) unsigned int*)(unsigned int)(uintptr_t)l,
      16, 0, 0);
}
__device__ __forceinline__ float dot4(float4 a, float4 b) {
  return a.x * b.x + a.y * b.y + a.z * b.z + a.w * b.w;
}

// ------------------- prep_w: weights pass (one launch) ---------------------
__global__ __launch_bounds__(256) void prep_w(
    const float* __restrict__ WQ, const float* __restrict__ WK,
    const float* __restrict__ WV, const float* __restrict__ WO,
    const float* __restrict__ WE, const float* __restrict__ WN,
    const float* __restrict__ wa, const float* __restrict__ bQ,
    const float* __restrict__ bK, const float* __restrict__ bV,
    const float* __restrict__ WEb, const float* __restrict__ WNb,
    const float* __restrict__ WAb,
    short* __restrict__ wqT, short* __restrict__ wkT,
    short* __restrict__ wvT, short* __restrict__ wo_bf,
    float* __restrict__ vE, float* __restrict__ vN,
    float* __restrict__ uQ, float* __restrict__ uK,
    float* __restrict__ c0, float* __restrict__ c1,
    float* __restrict__ bvw) {
  __shared__ short tile[64][65];
  __shared__ float redw[4];
  int bid = blockIdx.x, t = threadIdx.x;
  if (bid < 1024) {
    int z = bid >> 8, idx = bid & 255, bi = idx >> 4, bj = idx & 15;
    const float* src = z == 0 ? WQ : z == 1 ? WK : z == 2 ? WV : WO;
    if (z == 3) {
#pragma unroll
      for (int i = 0; i < 16; ++i) {
        int lin = i * 256 + t, r = lin >> 6, c = lin & 63;
        size_t idx2 = (size_t)(bi * 64 + r) * 1024 + bj * 64 + c;
        wo_bf[idx2] = (short)f2bf(src[idx2]);
      }
      return;
    }
    short* dst = z == 0 ? wqT : z == 1 ? wkT : wvT;
#pragma unroll
    for (int i = 0; i < 16; ++i) {
      int lin = i * 256 + t, r = lin >> 6, c = lin & 63;
      tile[r][c] = (short)f2bf(src[(size_t)(bi * 64 + r) * 1024 + bj * 64 + c]);
    }
    __syncthreads();
#pragma unroll
    for (int i = 0; i < 16; ++i) {
      int lin = i * 256 + t, r = lin >> 6, c = lin & 63;
      dst[(size_t)(bj * 64 + r) * 1024 + bi * 64 + c] = tile[c][r];
    }
  } else if (bid < 1280) {
    int idx = bid - 1024;
    int y = idx >> 6, ob = idx & 63;
    const float* M = y == 0 ? WE : y == 1 ? WN : y == 2 ? WQ : WK;
    const float* wv = (y < 2) ? wa : (y == 2 ? bK : bQ);
    float* dst = y == 0 ? vE : y == 1 ? vN : y == 2 ? uQ : uK;
    float a0 = 0.f, a1 = 0.f, a2 = 0.f, a3 = 0.f;
    int o0 = ob * 16;
#pragma unroll
    for (int i = 0; i < 16; ++i) {
      int o = o0 + i;
      float wvv = wv[o];
      const float* row = M + (size_t)o * 1024;
      a0 += wvv * row[t];
      a1 += wvv * row[t + 256];
      a2 += wvv * row[t + 512];
      a3 += wvv * row[t + 768];
    }
    atomicAdd(dst + t, a0);
    atomicAdd(dst + t + 256, a1);
    atomicAdd(dst + t + 512, a2);
    atomicAdd(dst + t + 768, a3);
  } else if (bid < 1282) {
    int which = bid - 1280;
    float a = 0.f;
    if (which == 0)
      for (int i = t; i < 1024; i += 256) a += wa[i] * (WEb[i] + WNb[i]);
    else
      for (int i = t; i < 1024; i += 256) a += bQ[i] * bK[i];
#pragma unroll
    for (int o = 32; o > 0; o >>= 1) a += __shfl_down(a, o, 64);
    if ((t & 63) == 0) redw[t >> 6] = a;
    __syncthreads();
    if (t == 0) {
      float tot = redw[0] + redw[1] + redw[2] + redw[3];
      if (which == 0) c0[0] = tot + WAb[0];
      else c1[0] = tot;
    }
  } else {
    int r = bid - 1282;
    float4 wv = ((const float4*)(WO + (size_t)r * 1024))[t];
    float4 bv = ((const float4*)bV)[t];
    float a = dot4(wv, bv);
#pragma unroll
    for (int o = 32; o > 0; o >>= 1) a += __shfl_down(a, o, 64);
    if ((t & 63) == 0) redw[t >> 6] = a;
    __syncthreads();
    if (t == 0) bvw[r] = redw[0] + redw[1] + redw[2] + redw[3];
  }
}

// ---- prep2: gemm_pre (128) || nn wave-rows (2048) || nt wave-rows (2048) --
__global__ __launch_bounds__(256) void prep2(
    const short* __restrict__ wqT, const short* __restrict__ wkT,
    const short* __restrict__ wvT, const short* __restrict__ wo_bf,
    short* __restrict__ M1, short* __restrict__ M2,
    const float* __restrict__ nn, const float* __restrict__ nt,
    const float* __restrict__ uK, const float* __restrict__ vE,
    short* __restrict__ xn, float* __restrict__ xk,
    float* __restrict__ xe) {
  __shared__ short sA[128 * 64];
  __shared__ short sB[128 * 64];
  int bid = blockIdx.x, tid = threadIdx.x;
  if (bid >= 128) {
    int lane = tid & 63, wv = tid >> 6;
    int isNT = bid >= 2176;
    int idx = bid - (isNT ? 2176 : 128);
    const float* srcm = isNT ? nt : nn;
    const float* vec = isNT ? vE : uK;
    const float4* v4 = (const float4*)vec + lane * 4;
    float4 u0 = v4[0], u1 = v4[1], u2 = v4[2], u3 = v4[3];
    int row = idx * 8 + wv * 2;
#pragma unroll
    for (int rr = 0; rr < 2; ++rr) {
      const float4* src = (const float4*)(srcm + (size_t)(row + rr) * 1024)
                          + lane * 4;
      float4 a0 = src[0], a1 = src[1], a2 = src[2], a3 = src[3];
      if (!isNT) {
        bfx8 o0, o1;
        o0[0] = (short)f2bf(a0.x); o0[1] = (short)f2bf(a0.y);
        o0[2] = (short)f2bf(a0.z); o0[3] = (short)f2bf(a0.w);
        o0[4] = (short)f2bf(a1.x); o0[5] = (short)f2bf(a1.y);
        o0[6] = (short)f2bf(a1.z); o0[7] = (short)f2bf(a1.w);
        o1[0] = (short)f2bf(a2.x); o1[1] = (short)f2bf(a2.y);
        o1[2] = (short)f2bf(a2.z); o1[3] = (short)f2bf(a2.w);
        o1[4] = (short)f2bf(a3.x); o1[5] = (short)f2bf(a3.y);
        o1[6] = (short)f2bf(a3.z); o1[7] = (short)f2bf(a3.w);
        bfx8* dst = (bfx8*)(xn + (size_t)(row + rr) * 1024 + lane * 16);
        dst[0] = o0; dst[1] = o1;
      }
      float a = dot4(a0, u0) + dot4(a1, u1) + dot4(a2, u2) + dot4(a3, u3);
#pragma unroll
      for (int o = 32; o > 0; o >>= 1) a += __shfl_xor(a, o, 64);
      if (lane == 0) (isNT ? xe : xk)[row + rr] = a;
    }
    return;
  }
  int z = bid >> 6, by = (bid >> 3) & 7, bx = bid & 7;
  const short* A = z ? wo_bf : wqT;
  const short* B = z ? wvT : wkT;
  short* D = z ? M2 : M1;
  int lane = tid & 63, w = tid >> 6;
  int wm = w >> 1, wn = w & 1;
  f32x4 acc[4][4] = {};
  int lrow = lane & 15, lk = (lane >> 4) * 8;
  int srow = lane >> 3, scol = (lane & 7) * 8;
  const short* Ag = A + (size_t)by * 128 * 1024;
  const short* Bg = B + (size_t)bx * 128 * 1024;
  for (int k0 = 0; k0 < 1024; k0 += 64) {
#pragma unroll
    for (int i = 0; i < 4; ++i) {
      int c = w * 4 + i;
      gload16(Ag + (size_t)(c * 8 + srow) * 1024 + k0 + scol, sA + c * 512);
      gload16(Bg + (size_t)(c * 8 + srow) * 1024 + k0 + scol, sB + c * 512);
    }
    __syncthreads();
#pragma unroll
    for (int kk = 0; kk < 64; kk += 32) {
      bfx8 af[4], bfr[4];
#pragma unroll
      for (int mi = 0; mi < 4; ++mi)
        af[mi] = *(const bfx8*)(sA + (wm * 64 + mi * 16 + lrow) * 64 + kk + lk);
#pragma unroll
      for (int nj = 0; nj < 4; ++nj)
        bfr[nj] = *(const bfx8*)(sB + (wn * 64 + nj * 16 + lrow) * 64 + kk + lk);
#pragma unroll
      for (int mi = 0; mi < 4; ++mi)
#pragma unroll
        for (int nj = 0; nj < 4; ++nj)
          acc[mi][nj] = __builtin_amdgcn_mfma_f32_16x16x32_bf16(
              af[mi], bfr[nj], acc[mi][nj], 0, 0, 0);
    }
    __syncthreads();
  }
  int r0 = by * 128 + wm * 64, cb2 = bx * 128 + wn * 64;
#pragma unroll
  for (int mi = 0; mi < 4; ++mi)
#pragma unroll
    for (int nj = 0; nj < 4; ++nj) {
      int col = cb2 + nj * 16 + lrow;
#pragma unroll
      for (int r = 0; r < 4; ++r) {
        int row = r0 + mi * 16 + (lane >> 4) * 4 + r;
        D[(size_t)row * 1024 + col] = (short)f2bf(acc[mi][nj][r]);
      }
    }
}

// ----------- fused main GEMM (128², 4 waves, SINGLE buffer) ----------------
// D = xn @ Bf^T, Bf=[M1;M2]. 32 KiB LDS -> ~4 blocks/CU; classic m97 loop:
// stage -> vmcnt(0)+barrier -> compute -> barrier. XOR-swizzle, setprio,
// XCD-chunked grid (16 consecutive works share an A panel).
__global__ __launch_bounds__(256, 4) void gemm_main(
    const short* __restrict__ A, const short* __restrict__ Bf,
    const float* __restrict__ bias2, const float* __restrict__ nodet,
    float* __restrict__ sPart, short* __restrict__ vw) {
  __shared__ short sA[8192];  // 128 rows x 64 cols, XOR-swizzled
  __shared__ short sB[8192];
  int tid = threadIdx.x;
  int lane = tid & 63, w = tid >> 6;   // 4 waves
  int wm = w >> 1, wn = w & 1;         // 2 x 2 wave grid, 64x64 each
  int wg = blockIdx.x;
  int work = (wg & 7) * 256 + (wg >> 3);  // XCD-chunked, bijective (2048%8==0)
  int by = work >> 4, bx = work & 15;     // 16 consecutive works share A panel
  int lrow = lane & 15, g = lane >> 4;
  int sw0 = g ^ (lrow & 7);            // swizzled slot, kk=0 half
  int sg = (lane & 7) ^ (lane >> 3);   // inverse-swizzled global col slot
  const short* Agt = A + ((size_t)(by * 128 + w * 32 + (lane >> 3))) * 1024 + sg * 8;
  const short* Bgt = Bf + ((size_t)(bx * 128 + w * 32 + (lane >> 3))) * 1024 + sg * 8;

  f32x4 acc[4][4] = {};
  int arow = wm * 64 + lrow, brow = wn * 64 + lrow;

  for (int kt = 0; kt < NT; ++kt) {
    {  // stage tile kt (8 x global_load_lds per wave-slice)
      const short* ag = Agt + kt * 64;
      const short* bg = Bgt + kt * 64;
#pragma unroll
      for (int i = 0; i < 4; ++i) {
        gload16(ag + i * 8192, &sA[w * 2048 + i * 512]);
        gload16(bg + i * 8192, &sB[w * 2048 + i * 512]);
      }
    }
    asm volatile("s_waitcnt vmcnt(0)" ::: "memory");
    __builtin_amdgcn_sched_barrier(0);
    __builtin_amdgcn_s_barrier();      // tile visible to all waves
    __builtin_amdgcn_sched_barrier(0);

    bfx8 bq[4][2];
#pragma unroll
    for (int nj = 0; nj < 4; ++nj) {
      bq[nj][0] = *(const bfx8*)(sB + (brow + nj * 16) * 64 + sw0 * 8);
      bq[nj][1] = *(const bfx8*)(sB + (brow + nj * 16) * 64 + (sw0 ^ 4) * 8);
    }
#pragma unroll
    for (int q = 0; q < 2; ++q) {  // 2 runs x 16 MFMA
      bfx8 a00 = *(const bfx8*)(sA + (arow + (2 * q) * 16) * 64 + sw0 * 8);
      bfx8 a01 = *(const bfx8*)(sA + (arow + (2 * q) * 16) * 64 + (sw0 ^ 4) * 8);
      bfx8 a10 = *(const bfx8*)(sA + (arow + (2 * q + 1) * 16) * 64 + sw0 * 8);
      bfx8 a11 = *(const bfx8*)(sA + (arow + (2 * q + 1) * 16) * 64 + (sw0 ^ 4) * 8);
      __builtin_amdgcn_s_setprio(1);
#pragma unroll
      for (int nj = 0; nj < 4; ++nj) {
        acc[2 * q][nj] = __builtin_amdgcn_mfma_f32_16x16x32_bf16(
            a00, bq[nj][0], acc[2 * q][nj], 0, 0, 0);
        acc[2 * q][nj] = __builtin_amdgcn_mfma_f32_16x16x32_bf16(
            a01, bq[nj][1], acc[2 * q][nj], 0, 0, 0);
        acc[2 * q + 1][nj] = __builtin_amdgcn_mfma_f32_16x16x32_bf16(
            a10, bq[nj][0], acc[2 * q + 1][nj], 0, 0, 0);
        acc[2 * q + 1][nj] = __builtin_amdgcn_mfma_f32_16x16x32_bf16(
            a11, bq[nj][1], acc[2 * q + 1][nj], 0, 0, 0);
      }
      __builtin_amdgcn_s_setprio(0);
    }
    __builtin_amdgcn_sched_barrier(0);
    __builtin_amdgcn_s_barrier();      // all reads done before next stage
    __builtin_amdgcn_sched_barrier(0);
  }

  int row0 = by * 128 + wm * 64;
  int cb = bx * 128 + wn * 64;  // column base in [0,2048)
  if (bx < 8) {
    // t-half: per-row 64-col partial of <node_t[row], t[row]+uQ>
    float bias_nj[4];
#pragma unroll
    for (int nj = 0; nj < 4; ++nj) bias_nj[nj] = bias2[cb + nj * 16 + lrow];
    int px = bx * 2 + wn;  // 16 partials per row
#pragma unroll
    for (int mi = 0; mi < 4; ++mi) {
#pragma unroll
      for (int r = 0; r < 4; ++r) {
        int row = row0 + mi * 16 + g * 4 + r;
        const float* xr = nodet + (size_t)row * 1024;
        float v = 0.f;
#pragma unroll
        for (int nj = 0; nj < 4; ++nj)
          v += (acc[mi][nj][r] + bias_nj[nj]) * xr[cb + nj * 16 + lrow];
        v += __shfl_xor(v, 1, 64);
        v += __shfl_xor(v, 2, 64);
        v += __shfl_xor(v, 4, 64);
        v += __shfl_xor(v, 8, 64);
        if (lrow == 0) sPart[(size_t)row * 16 + px] = v;
      }
    }
  } else {
#pragma unroll
    for (int mi = 0; mi < 4; ++mi)
#pragma unroll
      for (int nj = 0; nj < 4; ++nj) {
        int colv = cb - 1024 + nj * 16 + lrow;
        float bv = bias2[1024 + colv];
#pragma unroll
        for (int r = 0; r < 4; ++r) {
          int row = row0 + mi * 16 + g * 4 + r;
          vw[(size_t)row * 1024 + colv] = (short)f2bf(acc[mi][nj][r] + bv);
        }
      }
  }
}

// ---------- out2: sdiag + gelu-sum, wave-per-batch (512 thr, 1 sync) -------
__global__ __launch_bounds__(512) void out2_kernel(
    const short* __restrict__ vw, const float* __restrict__ sPart,
    const float* __restrict__ xe, const float* __restrict__ xk,
    const float* __restrict__ vN, const float* __restrict__ bO,
    const float* __restrict__ c0p, const float* __restrict__ c1p,
    float* __restrict__ out) {
  int n = blockIdx.x, t = threadIdx.x;
  __shared__ float sS[8];
  if (t < 128) {
    int b = t >> 4, j = t & 15;
    size_t row = (size_t)b * N_SEQ + n;
    float p = sPart[row * 16 + j];
    p += __shfl_xor(p, 1, 64);
    p += __shfl_xor(p, 2, 64);
    p += __shfl_xor(p, 4, 64);
    p += __shfl_xor(p, 8, 64);
    if (j == 0) sS[b] = p + xk[row] + c1p[0];
  }
  __syncthreads();
  int b = t >> 6, lane = t & 63;   // wave = batch
  float m = sS[0];
#pragma unroll
  for (int i = 1; i < 8; ++i) m = fmaxf(m, sS[i]);
  float sum = 0.f, eb = 0.f;
#pragma unroll
  for (int i = 0; i < 8; ++i) {
    float e = expf((sS[i] - m) * (1.0f / 128.0f));
    sum += e;
    if (i == b) eb = e;
  }
  float d = eb / sum;
  size_t row = (size_t)b * N_SEQ + n;
  const s16x4* vv = (const s16x4*)(vw + row * 1024 + lane * 16);
  const float4* bo4 = (const float4*)bO + lane * 4;
  const float4* vn4 = (const float4*)vN + lane * 4;
  float a = 0.f;
#pragma unroll
  for (int q = 0; q < 4; ++q) {
    s16x4 v = vv[q];
    float4 bo = bo4[q], vn = vn4[q];
    float gx;
    gx = fmaf(d, bf2f(v[0]), bo.x); a += gelu_exact(gx) * vn.x;
    gx = fmaf(d, bf2f(v[1]), bo.y); a += gelu_exact(gx) * vn.y;
    gx = fmaf(d, bf2f(v[2]), bo.z); a += gelu_exact(gx) * vn.z;
    gx = fmaf(d, bf2f(v[3]), bo.w); a += gelu_exact(gx) * vn.w;
  }
#pragma unroll
  for (int o = 32; o > 0; o >>= 1) a += __shfl_xor(a, o, 64);
  if (lane == 0) out[row] = xe[row] + c0p[0] + a;
}

// ---------------------------------------------------------------------------
extern "C" void kernel_launch(void* const* d_in, const int* in_sizes, int n_in,
                              void* d_out, int out_size, void* d_ws,
                              size_t ws_size, hipStream_t stream) {
  const float* nt  = (const float*)d_in[0];
  const float* nn  = (const float*)d_in[1];
  const float* WQ  = (const float*)d_in[2];
  const float* bQ  = (const float*)d_in[3];
  const float* WK  = (const float*)d_in[4];
  const float* bK  = (const float*)d_in[5];
  const float* WV  = (const float*)d_in[6];
  const float* bV  = (const float*)d_in[7];
  const float* WO  = (const float*)d_in[8];
  const float* bO  = (const float*)d_in[9];
  const float* WE  = (const float*)d_in[10];
  const float* WEb = (const float*)d_in[11];
  const float* WN  = (const float*)d_in[12];
  const float* WNb = (const float*)d_in[13];
  const float* wa  = (const float*)d_in[14];
  const float* WAb = (const float*)d_in[15];
  float* out = (float*)d_out;

  char* w = (char*)d_ws;
  size_t o = 0;
  const size_t BIG = (size_t)M_TOT * 1024 * 2;          // 33.55 MB
  short* xn     = (short*)(w + o); o += BIG;
  short* vw     = (short*)(w + o); o += BIG;
  short* Bf     = (short*)(w + o); o += (size_t)2048 * 1024 * 2;  // [M1;M2]
  short* wqT    = (short*)(w + o); o += 2097152;
  short* wkT    = (short*)(w + o); o += 2097152;
  short* wvT    = (short*)(w + o); o += 2097152;
  short* wo_bf  = (short*)(w + o); o += 2097152;
  float* sPart  = (float*)(w + o); o += (size_t)M_TOT * 16 * 4;   // 1 MB
  float* bias2  = (float*)(w + o); o += 8192;           // [uQ(1024); bvw(1024)]
  float* vE     = (float*)(w + o); o += 4096;
  float* vN     = (float*)(w + o); o += 4096;
  float* uK     = (float*)(w + o); o += 4096;
  float* xk     = (float*)(w + o); o += 65536;
  float* xe     = (float*)(w + o); o += 65536;
  float* c0     = (float*)(w + o); o += 256;
  float* c1     = (float*)(w + o); o += 256;
  (void)ws_size; (void)in_sizes; (void)n_in; (void)out_size;

  // zero atomic targets: bias2(uQ,bvw) + vE + vN + uK = 20 KB contiguous
  hipMemsetAsync(bias2, 0, 8192 + 4096 * 3, stream);

  prep_w<<<2306, 256, 0, stream>>>(WQ, WK, WV, WO, WE, WN, wa, bQ, bK, bV,
                                   WEb, WNb, WAb, wqT, wkT, wvT, wo_bf,
                                   vE, vN, bias2, uK, c0, c1, bias2 + 1024);
  prep2<<<4224, 256, 0, stream>>>(wqT, wkT, wvT, wo_bf, Bf, Bf + 1048576,
                                  nn, nt, uK, vE, xn, xk, xe);
  gemm_main<<<2048, 256, 0, stream>>>(xn, Bf, bias2, nt, sPart, vw);
  out2_kernel<<<N_SEQ, 512, 0, stream>>>(vw, sPart, xe, xk, vN, bO,
                                         c0, c1, out);
}

// Round 16
// 147.908 us; speedup vs baseline: 1.0196x; 1.0196x over previous
//
#include <hip/hip_runtime.h>
#include <cstdint>
#include <cstddef>

// ---------------------------------------------------------------------------
// Flow_24429773980225 — round 16: half-tile pipelined 256² GEMM (m201-style
// 4-phase/tile, dbuf×half LDS, counted vmcnt(4)); tail VERBATIM r15.
//   s[r]  = <node_t[r], t[r]> + <x_n[r], uK> + c1,  t = x_n@M1^T + uQ
//   M1    = WQ^T WK,  uQ = WQ^T bK,  uK = WK^T bQ,  c1 = <bQ,bK>
//   dg    = softmax_b(s/128)
//   vw    = x_n@M2^T + bvw,  M2 = WO·WV,  bvw = WO·bV
//   out[r]= xe[r] + c0 + sum_c gelu(dg[r]*vw[r,c] + bO[c])·vN[c]
// ---------------------------------------------------------------------------

typedef __attribute__((ext_vector_type(8))) short bfx8;   // 8 bf16
typedef __attribute__((ext_vector_type(4))) short s16x4;  // 4 bf16
typedef __attribute__((ext_vector_type(4))) float f32x4;  // MFMA acc

#define N_SEQ 2048
#define M_TOT 16384   // B*N
#define NT 16         // K / 64

__device__ __forceinline__ unsigned short f2bf(float f) {
  unsigned int u = __float_as_uint(f);
  return (unsigned short)((u + 0x7fffu + ((u >> 16) & 1u)) >> 16);  // RNE
}
__device__ __forceinline__ float bf2f(short s) {
  return __uint_as_float(((unsigned int)(unsigned short)s) << 16);
}
__device__ __forceinline__ float gelu_exact(float g) {
  return 0.5f * g * (1.0f + erff(g * 0.70710678118654752f));
}
__device__ __forceinline__ void gload16(const void* g, void* l) {
  __builtin_amdgcn_global_load_lds(
      (const __attribute__((address_space(1))) unsigned int*)g,
      (__attribute__((address_space(3))) unsigned int*)(unsigned int)(uintptr_t)l,
      16, 0, 0);
}
__device__ __forceinline__ float dot4(float4 a, float4 b) {
  return a.x * b.x + a.y * b.y + a.z * b.z + a.w * b.w;
}

// ------------------- prep_w: weights pass (one launch) ---------------------
__global__ __launch_bounds__(256) void prep_w(
    const float* __restrict__ WQ, const float* __restrict__ WK,
    const float* __restrict__ WV, const float* __restrict__ WO,
    const float* __restrict__ WE, const float* __restrict__ WN,
    const float* __restrict__ wa, const float* __restrict__ bQ,
    const float* __restrict__ bK, const float* __restrict__ bV,
    const float* __restrict__ WEb, const float* __restrict__ WNb,
    const float* __restrict__ WAb,
    short* __restrict__ wqT, short* __restrict__ wkT,
    short* __restrict__ wvT, short* __restrict__ wo_bf,
    float* __restrict__ vE, float* __restrict__ vN,
    float* __restrict__ uQ, float* __restrict__ uK,
    float* __restrict__ c0, float* __restrict__ c1,
    float* __restrict__ bvw) {
  __shared__ short tile[64][65];
  __shared__ float redw[4];
  int bid = blockIdx.x, t = threadIdx.x;
  if (bid < 1024) {
    int z = bid >> 8, idx = bid & 255, bi = idx >> 4, bj = idx & 15;
    const float* src = z == 0 ? WQ : z == 1 ? WK : z == 2 ? WV : WO;
    if (z == 3) {
#pragma unroll
      for (int i = 0; i < 16; ++i) {
        int lin = i * 256 + t, r = lin >> 6, c = lin & 63;
        size_t idx2 = (size_t)(bi * 64 + r) * 1024 + bj * 64 + c;
        wo_bf[idx2] = (short)f2bf(src[idx2]);
      }
      return;
    }
    short* dst = z == 0 ? wqT : z == 1 ? wkT : wvT;
#pragma unroll
    for (int i = 0; i < 16; ++i) {
      int lin = i * 256 + t, r = lin >> 6, c = lin & 63;
      tile[r][c] = (short)f2bf(src[(size_t)(bi * 64 + r) * 1024 + bj * 64 + c]);
    }
    __syncthreads();
#pragma unroll
    for (int i = 0; i < 16; ++i) {
      int lin = i * 256 + t, r = lin >> 6, c = lin & 63;
      dst[(size_t)(bj * 64 + r) * 1024 + bi * 64 + c] = tile[c][r];
    }
  } else if (bid < 1280) {
    int idx = bid - 1024;
    int y = idx >> 6, ob = idx & 63;
    const float* M = y == 0 ? WE : y == 1 ? WN : y == 2 ? WQ : WK;
    const float* wv = (y < 2) ? wa : (y == 2 ? bK : bQ);
    float* dst = y == 0 ? vE : y == 1 ? vN : y == 2 ? uQ : uK;
    float a0 = 0.f, a1 = 0.f, a2 = 0.f, a3 = 0.f;
    int o0 = ob * 16;
#pragma unroll
    for (int i = 0; i < 16; ++i) {
      int o = o0 + i;
      float wvv = wv[o];
      const float* row = M + (size_t)o * 1024;
      a0 += wvv * row[t];
      a1 += wvv * row[t + 256];
      a2 += wvv * row[t + 512];
      a3 += wvv * row[t + 768];
    }
    atomicAdd(dst + t, a0);
    atomicAdd(dst + t + 256, a1);
    atomicAdd(dst + t + 512, a2);
    atomicAdd(dst + t + 768, a3);
  } else if (bid < 1282) {
    int which = bid - 1280;
    float a = 0.f;
    if (which == 0)
      for (int i = t; i < 1024; i += 256) a += wa[i] * (WEb[i] + WNb[i]);
    else
      for (int i = t; i < 1024; i += 256) a += bQ[i] * bK[i];
#pragma unroll
    for (int o = 32; o > 0; o >>= 1) a += __shfl_down(a, o, 64);
    if ((t & 63) == 0) redw[t >> 6] = a;
    __syncthreads();
    if (t == 0) {
      float tot = redw[0] + redw[1] + redw[2] + redw[3];
      if (which == 0) c0[0] = tot + WAb[0];
      else c1[0] = tot;
    }
  } else {
    int r = bid - 1282;
    float4 wv = ((const float4*)(WO + (size_t)r * 1024))[t];
    float4 bv = ((const float4*)bV)[t];
    float a = dot4(wv, bv);
#pragma unroll
    for (int o = 32; o > 0; o >>= 1) a += __shfl_down(a, o, 64);
    if ((t & 63) == 0) redw[t >> 6] = a;
    __syncthreads();
    if (t == 0) bvw[r] = redw[0] + redw[1] + redw[2] + redw[3];
  }
}

// ---- prep2: gemm_pre (128) || nn wave-rows (2048) || nt wave-rows (2048) --
__global__ __launch_bounds__(256) void prep2(
    const short* __restrict__ wqT, const short* __restrict__ wkT,
    const short* __restrict__ wvT, const short* __restrict__ wo_bf,
    short* __restrict__ M1, short* __restrict__ M2,
    const float* __restrict__ nn, const float* __restrict__ nt,
    const float* __restrict__ uK, const float* __restrict__ vE,
    short* __restrict__ xn, float* __restrict__ xk,
    float* __restrict__ xe) {
  __shared__ short sA[128 * 64];
  __shared__ short sB[128 * 64];
  int bid = blockIdx.x, tid = threadIdx.x;
  if (bid >= 128) {
    int lane = tid & 63, wv = tid >> 6;
    int isNT = bid >= 2176;
    int idx = bid - (isNT ? 2176 : 128);
    const float* srcm = isNT ? nt : nn;
    const float* vec = isNT ? vE : uK;
    const float4* v4 = (const float4*)vec + lane * 4;
    float4 u0 = v4[0], u1 = v4[1], u2 = v4[2], u3 = v4[3];
    int row = idx * 8 + wv * 2;
#pragma unroll
    for (int rr = 0; rr < 2; ++rr) {
      const float4* src = (const float4*)(srcm + (size_t)(row + rr) * 1024)
                          + lane * 4;
      float4 a0 = src[0], a1 = src[1], a2 = src[2], a3 = src[3];
      if (!isNT) {
        bfx8 o0, o1;
        o0[0] = (short)f2bf(a0.x); o0[1] = (short)f2bf(a0.y);
        o0[2] = (short)f2bf(a0.z); o0[3] = (short)f2bf(a0.w);
        o0[4] = (short)f2bf(a1.x); o0[5] = (short)f2bf(a1.y);
        o0[6] = (short)f2bf(a1.z); o0[7] = (short)f2bf(a1.w);
        o1[0] = (short)f2bf(a2.x); o1[1] = (short)f2bf(a2.y);
        o1[2] = (short)f2bf(a2.z); o1[3] = (short)f2bf(a2.w);
        o1[4] = (short)f2bf(a3.x); o1[5] = (short)f2bf(a3.y);
        o1[6] = (short)f2bf(a3.z); o1[7] = (short)f2bf(a3.w);
        bfx8* dst = (bfx8*)(xn + (size_t)(row + rr) * 1024 + lane * 16);
        dst[0] = o0; dst[1] = o1;
      }
      float a = dot4(a0, u0) + dot4(a1, u1) + dot4(a2, u2) + dot4(a3, u3);
#pragma unroll
      for (int o = 32; o > 0; o >>= 1) a += __shfl_xor(a, o, 64);
      if (lane == 0) (isNT ? xe : xk)[row + rr] = a;
    }
    return;
  }
  int z = bid >> 6, by = (bid >> 3) & 7, bx = bid & 7;
  const short* A = z ? wo_bf : wqT;
  const short* B = z ? wvT : wkT;
  short* D = z ? M2 : M1;
  int lane = tid & 63, w = tid >> 6;
  int wm = w >> 1, wn = w & 1;
  f32x4 acc[4][4] = {};
  int lrow = lane & 15, lk = (lane >> 4) * 8;
  int srow = lane >> 3, scol = (lane & 7) * 8;
  const short* Ag = A + (size_t)by * 128 * 1024;
  const short* Bg = B + (size_t)bx * 128 * 1024;
  for (int k0 = 0; k0 < 1024; k0 += 64) {
#pragma unroll
    for (int i = 0; i < 4; ++i) {
      int c = w * 4 + i;
      gload16(Ag + (size_t)(c * 8 + srow) * 1024 + k0 + scol, sA + c * 512);
      gload16(Bg + (size_t)(c * 8 + srow) * 1024 + k0 + scol, sB + c * 512);
    }
    __syncthreads();
#pragma unroll
    for (int kk = 0; kk < 64; kk += 32) {
      bfx8 af[4], bfr[4];
#pragma unroll
      for (int mi = 0; mi < 4; ++mi)
        af[mi] = *(const bfx8*)(sA + (wm * 64 + mi * 16 + lrow) * 64 + kk + lk);
#pragma unroll
      for (int nj = 0; nj < 4; ++nj)
        bfr[nj] = *(const bfx8*)(sB + (wn * 64 + nj * 16 + lrow) * 64 + kk + lk);
#pragma unroll
      for (int mi = 0; mi < 4; ++mi)
#pragma unroll
        for (int nj = 0; nj < 4; ++nj)
          acc[mi][nj] = __builtin_amdgcn_mfma_f32_16x16x32_bf16(
              af[mi], bfr[nj], acc[mi][nj], 0, 0, 0);
    }
    __syncthreads();
  }
  int r0 = by * 128 + wm * 64, cb2 = bx * 128 + wn * 64;
#pragma unroll
  for (int mi = 0; mi < 4; ++mi)
#pragma unroll
    for (int nj = 0; nj < 4; ++nj) {
      int col = cb2 + nj * 16 + lrow;
#pragma unroll
      for (int r = 0; r < 4; ++r) {
        int row = r0 + mi * 16 + (lane >> 4) * 4 + r;
        D[(size_t)row * 1024 + col] = (short)f2bf(acc[mi][nj][r]);
      }
    }
}

// ---------- fused main GEMM: 256², 8 waves, half-tile pipeline -------------
// LDS [2 dbuf][2 half] per operand. Per K-tile t, 4 phases:
//   p0: read all B(t) frags + A-quad0; stage A(t+1)h0
//   p1: read A-quad1;                  stage A(t+1)h1
//   p2: read A-quad2;                  stage B(t+2)h0
//   p3: read A-quad3;                  stage B(t+2)h1; close: vmcnt(4)+bar
// Each phase: [reads][stage][bar][lgkmcnt(0)][setprio 16 MFMA]. vmcnt(4) at
// tile close => A(t+1) landed, B(t+2) halves stay in flight (T4 counted).
__global__ __launch_bounds__(512, 2) void gemm_main(
    const short* __restrict__ A, const short* __restrict__ Bf,
    const float* __restrict__ bias2, const float* __restrict__ nodet,
    float* __restrict__ sPart, short* __restrict__ vw) {
  __shared__ short sA[2][2][8192];  // [dbuf][half][128x64], XOR-swizzled
  __shared__ short sB[2][2][8192];
  int tid = threadIdx.x;
  int lane = tid & 63, w = tid >> 6;   // 8 waves
  int wm = w >> 2, wn = w & 3;         // 2 x 4 wave grid, 128x64 each
  int wg = blockIdx.x;
  int work = (wg & 7) * 64 + (wg >> 3);  // XCD-chunked, bijective
  int by = work >> 3, bx = work & 7;
  int lrow = lane & 15, g = lane >> 4;
  int sw0 = g ^ (lrow & 7);            // swizzled K-slot
  // staging geometry: thread tid covers row (i*64 + tid>>3), slot tid&7
  int strow = tid >> 3;                // 0..63
  int sgc = (tid & 7) ^ (strow & 7);   // inverse-swizzled global slot
  const short* Abase = A + (size_t)(by * 256 + strow) * 1024 + sgc * 8;
  const short* Bbase = Bf + (size_t)(bx * 256 + strow) * 1024 + sgc * 8;
  int lbase = w * 512;                 // per-wave-uniform LDS elem base

  f32x4 acc[8][4] = {};

  auto stageA = [&](int db, int h, int kt) {
#pragma unroll
    for (int i = 0; i < 2; ++i)
      gload16(Abase + (size_t)(h * 128 + i * 64) * 1024 + kt * 64,
              &sA[db][h][i * 4096 + lbase]);
  };
  auto stageB = [&](int db, int h, int kt) {
#pragma unroll
    for (int i = 0; i < 2; ++i)
      gload16(Bbase + (size_t)(h * 128 + i * 64) * 1024 + kt * 64,
              &sB[db][h][i * 4096 + lbase]);
  };

  // prologue: A(0), B(0), B(1)  (12 loads/wave); wait all but B(1)
  stageA(0, 0, 0); stageA(0, 1, 0);
  stageB(0, 0, 0); stageB(0, 1, 0);
  stageB(1, 0, 1); stageB(1, 1, 1);
  asm volatile("s_waitcnt vmcnt(4)" ::: "memory");
  __builtin_amdgcn_sched_barrier(0);
  __builtin_amdgcn_s_barrier();        // A(0),B(0) visible
  __builtin_amdgcn_sched_barrier(0);

  int bh = wn >> 1, brw = (wn & 1) * 64 + lrow;  // wave's B half/row base
  for (int kt = 0; kt < NT; ++kt) {
    int db = kt & 1;
    const short* sa = &sA[db][wm][0];
    const short* sb = &sB[db][bh][0];
    bfx8 bq[4][2];
#pragma unroll
    for (int p = 0; p < 4; ++p) {
      // --- phase reads ---
      if (p == 0) {
#pragma unroll
        for (int nj = 0; nj < 4; ++nj) {
          bq[nj][0] = *(const bfx8*)(sb + (brw + nj * 16) * 64 + sw0 * 8);
          bq[nj][1] = *(const bfx8*)(sb + (brw + nj * 16) * 64 + (sw0 ^ 4) * 8);
        }
      }
      bfx8 a00 = *(const bfx8*)(sa + ((2 * p) * 16 + lrow) * 64 + sw0 * 8);
      bfx8 a01 = *(const bfx8*)(sa + ((2 * p) * 16 + lrow) * 64 + (sw0 ^ 4) * 8);
      bfx8 a10 = *(const bfx8*)(sa + ((2 * p + 1) * 16 + lrow) * 64 + sw0 * 8);
      bfx8 a11 = *(const bfx8*)(sa + ((2 * p + 1) * 16 + lrow) * 64 + (sw0 ^ 4) * 8);
      // --- phase stage (one half-tile) ---
      if (p == 0 && kt + 1 < NT) stageA(db ^ 1, 0, kt + 1);
      if (p == 1 && kt + 1 < NT) stageA(db ^ 1, 1, kt + 1);
      if (p == 2 && kt + 2 < NT) stageB(db, 0, kt + 2);
      if (p == 3 && kt + 2 < NT) stageB(db, 1, kt + 2);
      __builtin_amdgcn_sched_barrier(0);
      __builtin_amdgcn_s_barrier();
      asm volatile("s_waitcnt lgkmcnt(0)" ::: "memory");
      __builtin_amdgcn_sched_barrier(0);
      __builtin_amdgcn_s_setprio(1);
#pragma unroll
      for (int nj = 0; nj < 4; ++nj) {
        acc[2 * p][nj] = __builtin_amdgcn_mfma_f32_16x16x32_bf16(
            a00, bq[nj][0], acc[2 * p][nj], 0, 0, 0);
        acc[2 * p][nj] = __builtin_amdgcn_mfma_f32_16x16x32_bf16(
            a01, bq[nj][1], acc[2 * p][nj], 0, 0, 0);
        acc[2 * p + 1][nj] = __builtin_amdgcn_mfma_f32_16x16x32_bf16(
            a10, bq[nj][0], acc[2 * p + 1][nj], 0, 0, 0);
        acc[2 * p + 1][nj] = __builtin_amdgcn_mfma_f32_16x16x32_bf16(
            a11, bq[nj][1], acc[2 * p + 1][nj], 0, 0, 0);
      }
      __builtin_amdgcn_s_setprio(0);
      __builtin_amdgcn_sched_barrier(0);
    }
    // tile close: A(t+1) must be resident; B(t+2) halves may stay in flight
    if (kt < NT - 2)       asm volatile("s_waitcnt vmcnt(4)" ::: "memory");
    else if (kt == NT - 2) asm volatile("s_waitcnt vmcnt(0)" ::: "memory");
    __builtin_amdgcn_sched_barrier(0);
    __builtin_amdgcn_s_barrier();
    __builtin_amdgcn_sched_barrier(0);
  }

  int row0 = by * 256 + wm * 128;
  int cb = bx * 256 + wn * 64;  // column base in [0,2048)
  if (bx < 4) {
    // t-half: per-row 64-col partial of <node_t[row], t[row]+uQ>
    float bias_nj[4];
#pragma unroll
    for (int nj = 0; nj < 4; ++nj) bias_nj[nj] = bias2[cb + nj * 16 + lrow];
    int px = bx * 4 + wn;  // 16 partials per row
#pragma unroll
    for (int mi = 0; mi < 8; ++mi) {
#pragma unroll
      for (int r = 0; r < 4; ++r) {
        int row = row0 + mi * 16 + g * 4 + r;
        const float* xr = nodet + (size_t)row * 1024;
        float v = 0.f;
#pragma unroll
        for (int nj = 0; nj < 4; ++nj)
          v += (acc[mi][nj][r] + bias_nj[nj]) * xr[cb + nj * 16 + lrow];
        v += __shfl_xor(v, 1, 64);
        v += __shfl_xor(v, 2, 64);
        v += __shfl_xor(v, 4, 64);
        v += __shfl_xor(v, 8, 64);
        if (lrow == 0) sPart[(size_t)row * 16 + px] = v;
      }
    }
  } else {
#pragma unroll
    for (int mi = 0; mi < 8; ++mi)
#pragma unroll
      for (int nj = 0; nj < 4; ++nj) {
        int colv = cb - 1024 + nj * 16 + lrow;
        float bv = bias2[1024 + colv];
#pragma unroll
        for (int r = 0; r < 4; ++r) {
          int row = row0 + mi * 16 + g * 4 + r;
          vw[(size_t)row * 1024 + colv] = (short)f2bf(acc[mi][nj][r] + bv);
        }
      }
  }
}

// ---------- out2: sdiag + gelu-sum, wave-per-batch (512 thr, 1 sync) -------
__global__ __launch_bounds__(512) void out2_kernel(
    const short* __restrict__ vw, const float* __restrict__ sPart,
    const float* __restrict__ xe, const float* __restrict__ xk,
    const float* __restrict__ vN, const float* __restrict__ bO,
    const float* __restrict__ c0p, const float* __restrict__ c1p,
    float* __restrict__ out) {
  int n = blockIdx.x, t = threadIdx.x;
  __shared__ float sS[8];
  if (t < 128) {
    int b = t >> 4, j = t & 15;
    size_t row = (size_t)b * N_SEQ + n;
    float p = sPart[row * 16 + j];
    p += __shfl_xor(p, 1, 64);
    p += __shfl_xor(p, 2, 64);
    p += __shfl_xor(p, 4, 64);
    p += __shfl_xor(p, 8, 64);
    if (j == 0) sS[b] = p + xk[row] + c1p[0];
  }
  __syncthreads();
  int b = t >> 6, lane = t & 63;   // wave = batch
  float m = sS[0];
#pragma unroll
  for (int i = 1; i < 8; ++i) m = fmaxf(m, sS[i]);
  float sum = 0.f, eb = 0.f;
#pragma unroll
  for (int i = 0; i < 8; ++i) {
    float e = expf((sS[i] - m) * (1.0f / 128.0f));
    sum += e;
    if (i == b) eb = e;
  }
  float d = eb / sum;
  size_t row = (size_t)b * N_SEQ + n;
  const s16x4* vv = (const s16x4*)(vw + row * 1024 + lane * 16);
  const float4* bo4 = (const float4*)bO + lane * 4;
  const float4* vn4 = (const float4*)vN + lane * 4;
  float a = 0.f;
#pragma unroll
  for (int q = 0; q < 4; ++q) {
    s16x4 v = vv[q];
    float4 bo = bo4[q], vn = vn4[q];
    float gx;
    gx = fmaf(d, bf2f(v[0]), bo.x); a += gelu_exact(gx) * vn.x;
    gx = fmaf(d, bf2f(v[1]), bo.y); a += gelu_exact(gx) * vn.y;
    gx = fmaf(d, bf2f(v[2]), bo.z); a += gelu_exact(gx) * vn.z;
    gx = fmaf(d, bf2f(v[3]), bo.w); a += gelu_exact(gx) * vn.w;
  }
#pragma unroll
  for (int o = 32; o > 0; o >>= 1) a += __shfl_xor(a, o, 64);
  if (lane == 0) out[row] = xe[row] + c0p[0] + a;
}

// ---------------------------------------------------------------------------
extern "C" void kernel_launch(void* const* d_in, const int* in_sizes, int n_in,
                              void* d_out, int out_size, void* d_ws,
                              size_t ws_size, hipStream_t stream) {
  const float* nt  = (const float*)d_in[0];
  const float* nn  = (const float*)d_in[1];
  const float* WQ  = (const float*)d_in[2];
  const float* bQ  = (const float*)d_in[3];
  const float* WK  = (const float*)d_in[4];
  const float* bK  = (const float*)d_in[5];
  const float* WV  = (const float*)d_in[6];
  const float* bV  = (const float*)d_in[7];
  const float* WO  = (const float*)d_in[8];
  const float* bO  = (const float*)d_in[9];
  const float* WE  = (const float*)d_in[10];
  const float* WEb = (const float*)d_in[11];
  const float* WN  = (const float*)d_in[12];
  const float* WNb = (const float*)d_in[13];
  const float* wa  = (const float*)d_in[14];
  const float* WAb = (const float*)d_in[15];
  float* out = (float*)d_out;

  char* w = (char*)d_ws;
  size_t o = 0;
  const size_t BIG = (size_t)M_TOT * 1024 * 2;          // 33.55 MB
  short* xn     = (short*)(w + o); o += BIG;
  short* vw     = (short*)(w + o); o += BIG;
  short* Bf     = (short*)(w + o); o += (size_t)2048 * 1024 * 2;  // [M1;M2]
  short* wqT    = (short*)(w + o); o += 2097152;
  short* wkT    = (short*)(w + o); o += 2097152;
  short* wvT    = (short*)(w + o); o += 2097152;
  short* wo_bf  = (short*)(w + o); o += 2097152;
  float* sPart  = (float*)(w + o); o += (size_t)M_TOT * 16 * 4;   // 1 MB
  float* bias2  = (float*)(w + o); o += 8192;           // [uQ(1024); bvw(1024)]
  float* vE     = (float*)(w + o); o += 4096;
  float* vN     = (float*)(w + o); o += 4096;
  float* uK     = (float*)(w + o); o += 4096;
  float* xk     = (float*)(w + o); o += 65536;
  float* xe     = (float*)(w + o); o += 65536;
  float* c0     = (float*)(w + o); o += 256;
  float* c1     = (float*)(w + o); o += 256;
  (void)ws_size; (void)in_sizes; (void)n_in; (void)out_size;

  // zero atomic targets: bias2(uQ,bvw) + vE + vN + uK = 20 KB contiguous
  hipMemsetAsync(bias2, 0, 8192 + 4096 * 3, stream);

  prep_w<<<2306, 256, 0, stream>>>(WQ, WK, WV, WO, WE, WN, wa, bQ, bK, bV,
                                   WEb, WNb, WAb, wqT, wkT, wvT, wo_bf,
                                   vE, vN, bias2, uK, c0, c1, bias2 + 1024);
  prep2<<<4224, 256, 0, stream>>>(wqT, wkT, wvT, wo_bf, Bf, Bf + 1048576,
                                  nn, nt, uK, vE, xn, xk, xe);
  gemm_main<<<512, 512, 0, stream>>>(xn, Bf, bias2, nt, sPart, vw);
  out2_kernel<<<N_SEQ, 512, 0, stream>>>(vw, sPart, xe, xk, vN, bO,
                                         c0, c1, out);
}